// Round 2
// baseline (1055.810 us; speedup 1.0000x reference)
//
#include <hip/hip_runtime.h>
#include <math.h>

#define B_ 64
#define T_ 1024
#define D_ 256
#define U_ 256

typedef _Float16 h2_t  __attribute__((ext_vector_type(2)));
typedef _Float16 f16x8 __attribute__((ext_vector_type(8)));
typedef float    f32x4 __attribute__((ext_vector_type(4)));

// ---------------------------------------------------------------------------
// Kernel 1: proj = inputs @ W_xh + b_h, written into d_out (reused as xW buf).
// (unchanged — isolate the rnn_scan MFMA rewrite this round)
// ---------------------------------------------------------------------------
#define BM 64
#define BN 64
#define BK 16

__global__ __launch_bounds__(256, 2)
void proj_gemm(const float* __restrict__ A,      // [M, D_] inputs
               const float* __restrict__ Bm,     // [D_, U_] W_xh
               const float* __restrict__ bias,   // [U_]
               float* __restrict__ C) {          // [M, U_] out
    __shared__ float As[BK][BM];   // transposed A tile: As[k][m]
    __shared__ float Bs[BK][BN];

    const int m0 = blockIdx.x * BM;
    const int n0 = blockIdx.y * BN;
    const int tid = (int)threadIdx.x;
    const int tx = tid & 15;
    const int ty = tid >> 4;

    const int ar  = tid >> 2;
    const int akq = tid & 3;
    const int bk  = tid >> 4;
    const int bnq = tid & 15;

    float acc[4][4] = {};

    for (int k0 = 0; k0 < D_; k0 += BK) {
        float4 av = *(const float4*)&A[(size_t)(m0 + ar) * D_ + k0 + akq * 4];
        float4 bv = *(const float4*)&Bm[(size_t)(k0 + bk) * U_ + n0 + bnq * 4];
        __syncthreads();
        As[akq * 4 + 0][ar] = av.x;
        As[akq * 4 + 1][ar] = av.y;
        As[akq * 4 + 2][ar] = av.z;
        As[akq * 4 + 3][ar] = av.w;
        *(float4*)&Bs[bk][bnq * 4] = bv;
        __syncthreads();
        #pragma unroll
        for (int kk = 0; kk < BK; ++kk) {
            float4 a = *(const float4*)&As[kk][ty * 4];
            float4 b = *(const float4*)&Bs[kk][tx * 4];
            acc[0][0] = fmaf(a.x, b.x, acc[0][0]);
            acc[0][1] = fmaf(a.x, b.y, acc[0][1]);
            acc[0][2] = fmaf(a.x, b.z, acc[0][2]);
            acc[0][3] = fmaf(a.x, b.w, acc[0][3]);
            acc[1][0] = fmaf(a.y, b.x, acc[1][0]);
            acc[1][1] = fmaf(a.y, b.y, acc[1][1]);
            acc[1][2] = fmaf(a.y, b.z, acc[1][2]);
            acc[1][3] = fmaf(a.y, b.w, acc[1][3]);
            acc[2][0] = fmaf(a.z, b.x, acc[2][0]);
            acc[2][1] = fmaf(a.z, b.y, acc[2][1]);
            acc[2][2] = fmaf(a.z, b.z, acc[2][2]);
            acc[2][3] = fmaf(a.z, b.w, acc[2][3]);
            acc[3][0] = fmaf(a.w, b.x, acc[3][0]);
            acc[3][1] = fmaf(a.w, b.y, acc[3][1]);
            acc[3][2] = fmaf(a.w, b.z, acc[3][2]);
            acc[3][3] = fmaf(a.w, b.w, acc[3][3]);
        }
    }

    const float4 bb = *(const float4*)&bias[n0 + tx * 4];
    #pragma unroll
    for (int i = 0; i < 4; ++i) {
        const int row = m0 + ty * 4 + i;
        float4 o;
        o.x = acc[i][0] + bb.x;
        o.y = acc[i][1] + bb.y;
        o.z = acc[i][2] + bb.z;
        o.w = acc[i][3] + bb.w;
        *(float4*)&C[(size_t)row * U_ + n0 + tx * 4] = o;
    }
}

// ---------------------------------------------------------------------------
// branch-free fast tanh: tanh(x) = 1 - 2/(1 + e^{2x}).
// Saturates correctly at both ends in f32 (e^{2x} -> inf => 1; -> 0 => -1).
// Same math as the previously validated fast_tanh, minus abs/copysign.
// ---------------------------------------------------------------------------
__device__ __forceinline__ float fast_tanh2(float x) {
    float e = __expf(2.0f * x);
    return 1.0f - 2.0f * __builtin_amdgcn_rcpf(e + 1.0f);
}

// neighbor (lane^1) value via DPP quad_perm(1,0,3,2)
__device__ __forceinline__ float nbr1(float x) {
    return __int_as_float(__builtin_amdgcn_update_dpp(
            0, __float_as_int(x), 0xB1, 0xF, 0xF, true));
}

// ---------------------------------------------------------------------------
// Kernel 2: recurrence on the MFMA pipe.
// 4 blocks x 16 batches (M dim of mfma = batch). 512 threads = 8 waves,
// wave w owns output cols [32w, 32w+32) (2 n-tiles of 16).
// Per step per wave: 8 ds_read_b128 (A = h, all 16 batches, XOR-swizzled)
// + 16 mfma_f32_16x16x32_f16 (B = W_hh slice, resident in 64 VGPRs)
// + 8 tanh + 8 global stores (h out) + DPP/cvt_pkrtz pack + 4 ds_write_b32.
// xW is prefetched distance-2 from global straight into the mfma C operand.
// ONE raw s_barrier per step (lgkmcnt-only drain: vmcnt stays in flight so
// the prefetch isn't drained every step like __syncthreads would).
// h LDS layout: hl[hp][m][u] f16, byte = m*512 + ((u*2) ^ ((m&7)<<4))
// -> A-reads and pair-writes are both <=2-way bank conflicts (free).
// ---------------------------------------------------------------------------
#define MB_  16
#define NT2_ 512

__global__ __launch_bounds__(NT2_) __attribute__((amdgpu_waves_per_eu(2, 2)))
void rnn_scan(const float* __restrict__ W_hh,   // [U_, U_]
              float* __restrict__ out) {        // [B_, T_, U_]: xW in, h out
    const int tid  = (int)threadIdx.x;
    const int w    = tid >> 6;         // wave 0..7
    const int lane = tid & 63;
    const int g    = lane >> 4;        // 0..3 (k-group / row-group)
    const int c    = lane & 15;        // 0..15 (A-row=batch on reads, col on D)
    const int pe   = lane & 1;
    const int b0   = (int)blockIdx.x * MB_;
    const int n0   = w * 32;

    __shared__ __align__(16) _Float16 hl[2][MB_][U_];   // 16 KB, swizzled

    // ---- W_hh B-fragments in registers: bf[kt][nt], elem j = W[kt*32+g*8+j][n]
    f16x8 bf[8][2];
    #pragma unroll
    for (int kt = 0; kt < 8; ++kt) {
        #pragma unroll
        for (int nt = 0; nt < 2; ++nt) {
            f16x8 v;
            #pragma unroll
            for (int j = 0; j < 8; ++j)
                v[j] = (_Float16)W_hh[(size_t)(kt * 32 + g * 8 + j) * U_
                                      + (n0 + nt * 16 + c)];
            bf[kt][nt] = v;
        }
    }

    // zero h buffer [0] (8 KB = 512 threads x 16 B); zeros are swizzle-neutral
    ((int4*)&hl[0][0][0])[tid] = make_int4(0, 0, 0, 0);

    // per-lane global float offsets for the 8 (nt,r) D elements at t=0
    int gofs[2][4];
    #pragma unroll
    for (int nt = 0; nt < 2; ++nt)
        #pragma unroll
        for (int r = 0; r < 4; ++r)
            gofs[nt][r] = ((b0 + g * 4 + r) * T_) * U_ + (n0 + nt * 16 + c);

    // A-read byte offsets (loop-invariant): row c, cols kt*32+g*8 .. +8
    const int aswz = (c & 7) << 4;
    int ab[8];
    #pragma unroll
    for (int kt = 0; kt < 8; ++kt)
        ab[kt] = c * 512 + ((kt * 64 + g * 16) ^ aswz);

    // h-write byte offsets: row m = g*4+r; even lanes write tile0 pair (c,c+1),
    // odd lanes tile1 pair (c-1,c) -> 64 distinct b32 targets per r
    int wb[4];
    #pragma unroll
    for (int r = 0; r < 4; ++r) {
        const int m    = g * 4 + r;
        const int colb = n0 + pe * 16 + (c & ~1);
        wb[r] = m * 512 + ((colb * 2) ^ ((m & 7) << 4));
    }

    // preload xW fragments for t=0 and t=1
    f32x4 xwA[2], xwB[2];
    #pragma unroll
    for (int nt = 0; nt < 2; ++nt)
        #pragma unroll
        for (int r = 0; r < 4; ++r) {
            xwA[nt][r] = out[gofs[nt][r]];
            xwB[nt][r] = out[gofs[nt][r] + U_];
        }

    char* hbase = (char*)&hl[0][0][0];

    asm volatile("s_waitcnt lgkmcnt(0)" ::: "memory");
    __builtin_amdgcn_s_barrier();
    asm volatile("" ::: "memory");

#define RNN_STEP(XW, RDOFF, WROFF, TOFS)                                      \
    {                                                                         \
        f32x4 acc0 = XW[0], acc1 = XW[1];                                     \
        if (t + (TOFS) + 2 < T_) {  /* distance-2 xW prefetch */              \
            _Pragma("unroll") for (int nt = 0; nt < 2; ++nt)                  \
                _Pragma("unroll") for (int r = 0; r < 4; ++r)                 \
                    XW[nt][r] = out[gofs[nt][r] + ((TOFS) + 2) * U_];         \
        }                                                                     \
        _Pragma("unroll") for (int kt = 0; kt < 8; ++kt) {                    \
            f16x8 a = *(const f16x8*)(hbase + (RDOFF) + ab[kt]);              \
            acc0 = __builtin_amdgcn_mfma_f32_16x16x32_f16(a, bf[kt][0], acc0, \
                                                          0, 0, 0);           \
            acc1 = __builtin_amdgcn_mfma_f32_16x16x32_f16(a, bf[kt][1], acc1, \
                                                          0, 0, 0);           \
        }                                                                     \
        float h0[4], h1[4];                                                   \
        _Pragma("unroll") for (int r = 0; r < 4; ++r) {                       \
            h0[r] = fast_tanh2(acc0[r]);                                      \
            h1[r] = fast_tanh2(acc1[r]);                                      \
            out[gofs[0][r] + (TOFS) * U_] = h0[r];                            \
            out[gofs[1][r] + (TOFS) * U_] = h1[r];                            \
        }                                                                     \
        _Pragma("unroll") for (int r = 0; r < 4; ++r) {                       \
            float q0 = nbr1(h0[r]), q1 = nbr1(h1[r]);                         \
            auto pk = pe ? __builtin_amdgcn_cvt_pkrtz(q1, h1[r])              \
                         : __builtin_amdgcn_cvt_pkrtz(h0[r], q0);             \
            *(decltype(pk)*)(hbase + (WROFF) + wb[r]) = pk;                   \
        }                                                                     \
        asm volatile("s_waitcnt lgkmcnt(0)" ::: "memory");                    \
        __builtin_amdgcn_s_barrier();                                         \
        asm volatile("" ::: "memory");                                        \
    }

    for (int t = 0; t < T_; t += 2) {
        RNN_STEP(xwA, 0, 8192, 0)        // even step: read hl[0], write hl[1]
        RNN_STEP(xwB, 8192, 0, 1)        // odd  step: read hl[1], write hl[0]
        #pragma unroll
        for (int nt = 0; nt < 2; ++nt)
            #pragma unroll
            for (int r = 0; r < 4; ++r)
                gofs[nt][r] += 2 * U_;
    }
#undef RNN_STEP
}

// ---------------------------------------------------------------------------
extern "C" void kernel_launch(void* const* d_in, const int* in_sizes, int n_in,
                              void* d_out, int out_size, void* d_ws, size_t ws_size,
                              hipStream_t stream) {
    const float* inputs = (const float*)d_in[0];   // [B, T, D]
    const float* W_xh   = (const float*)d_in[1];   // [D, U]
    const float* W_hh   = (const float*)d_in[2];   // [U, U]
    const float* b_h    = (const float*)d_in[3];   // [U]
    float* out = (float*)d_out;                    // [B, T, U]

    const int M = B_ * T_;                         // 65536
    dim3 g1(M / BM, U_ / BN);                      // (1024, 4)
    proj_gemm<<<g1, 256, 0, stream>>>(inputs, W_xh, b_h, out);
    rnn_scan<<<B_ / MB_, NT2_, 0, stream>>>(W_hh, out);
}

// Round 3
// 681.013 us; speedup vs baseline: 1.5504x; 1.5504x over previous
//
#include <hip/hip_runtime.h>
#include <math.h>

#define B_ 64
#define T_ 1024
#define D_ 256
#define U_ 256

typedef _Float16 f16x8 __attribute__((ext_vector_type(8)));
typedef float    f32x4 __attribute__((ext_vector_type(4)));

// ---------------------------------------------------------------------------
// Kernel 1: proj = inputs @ W_xh + b_h, written into d_out (reused as xW buf).
// (unchanged — isolate the rnn_scan restructure this round)
// ---------------------------------------------------------------------------
#define BM 64
#define BN 64
#define BK 16

__global__ __launch_bounds__(256, 2)
void proj_gemm(const float* __restrict__ A,      // [M, D_] inputs
               const float* __restrict__ Bm,     // [D_, U_] W_xh
               const float* __restrict__ bias,   // [U_]
               float* __restrict__ C) {          // [M, U_] out
    __shared__ float As[BK][BM];   // transposed A tile: As[k][m]
    __shared__ float Bs[BK][BN];

    const int m0 = blockIdx.x * BM;
    const int n0 = blockIdx.y * BN;
    const int tid = (int)threadIdx.x;
    const int tx = tid & 15;
    const int ty = tid >> 4;

    const int ar  = tid >> 2;
    const int akq = tid & 3;
    const int bk  = tid >> 4;
    const int bnq = tid & 15;

    float acc[4][4] = {};

    for (int k0 = 0; k0 < D_; k0 += BK) {
        float4 av = *(const float4*)&A[(size_t)(m0 + ar) * D_ + k0 + akq * 4];
        float4 bv = *(const float4*)&Bm[(size_t)(k0 + bk) * U_ + n0 + bnq * 4];
        __syncthreads();
        As[akq * 4 + 0][ar] = av.x;
        As[akq * 4 + 1][ar] = av.y;
        As[akq * 4 + 2][ar] = av.z;
        As[akq * 4 + 3][ar] = av.w;
        *(float4*)&Bs[bk][bnq * 4] = bv;
        __syncthreads();
        #pragma unroll
        for (int kk = 0; kk < BK; ++kk) {
            float4 a = *(const float4*)&As[kk][ty * 4];
            float4 b = *(const float4*)&Bs[kk][tx * 4];
            acc[0][0] = fmaf(a.x, b.x, acc[0][0]);
            acc[0][1] = fmaf(a.x, b.y, acc[0][1]);
            acc[0][2] = fmaf(a.x, b.z, acc[0][2]);
            acc[0][3] = fmaf(a.x, b.w, acc[0][3]);
            acc[1][0] = fmaf(a.y, b.x, acc[1][0]);
            acc[1][1] = fmaf(a.y, b.y, acc[1][1]);
            acc[1][2] = fmaf(a.y, b.z, acc[1][2]);
            acc[1][3] = fmaf(a.y, b.w, acc[1][3]);
            acc[2][0] = fmaf(a.z, b.x, acc[2][0]);
            acc[2][1] = fmaf(a.z, b.y, acc[2][1]);
            acc[2][2] = fmaf(a.z, b.z, acc[2][2]);
            acc[2][3] = fmaf(a.z, b.w, acc[2][3]);
            acc[3][0] = fmaf(a.w, b.x, acc[3][0]);
            acc[3][1] = fmaf(a.w, b.y, acc[3][1]);
            acc[3][2] = fmaf(a.w, b.z, acc[3][2]);
            acc[3][3] = fmaf(a.w, b.w, acc[3][3]);
        }
    }

    const float4 bb = *(const float4*)&bias[n0 + tx * 4];
    #pragma unroll
    for (int i = 0; i < 4; ++i) {
        const int row = m0 + ty * 4 + i;
        float4 o;
        o.x = acc[i][0] + bb.x;
        o.y = acc[i][1] + bb.y;
        o.z = acc[i][2] + bb.z;
        o.w = acc[i][3] + bb.w;
        *(float4*)&C[(size_t)row * U_ + n0 + tx * 4] = o;
    }
}

// ---------------------------------------------------------------------------
// branch-free fast tanh: tanh(x) = 1 - 2/(1 + e^{2x}). (validated R2)
// ---------------------------------------------------------------------------
__device__ __forceinline__ float fast_tanh2(float x) {
    float e = __expf(2.0f * x);
    return 1.0f - 2.0f * __builtin_amdgcn_rcpf(e + 1.0f);
}

// ---------------------------------------------------------------------------
// Kernel 2: recurrence on the MFMA pipe, 64 blocks (1 batch each, 64 CUs).
// M-dim of mfma filled with REPLICATED rows (all rows = h of this batch):
//   * A-fragment reads are 16-lane-broadcast ds_read_b128 from a linear
//     512 B h buffer — no transpose, no swizzle, no conflicts (unique data
//     512 B/wave/step vs R2's 8 KB distinct-address reads = its 768-cyc
//     LDS floor).
//   * D rows are all equal -> only reg 0 live: 2 tanh/lane/step (vs 8).
//   * chunked xW/h staging (R1-proven): NO global ops inside the step loop.
//   * h double-buffered (2x512 B) -> ONE raw s_barrier (lgkmcnt-only) per
//     step; one more per 16-step chunk boundary.
// Per wave/step: 8 broadcast b128 + 2 b32 reads, 16 mfma (2 n-tiles x 8 k),
// 2 add + 2 tanh, 4 masked LDS writes.
// ---------------------------------------------------------------------------
#define CH_  16
#define NCH_ (T_ / CH_)
#define NT2_ 512

__global__ __launch_bounds__(NT2_) __attribute__((amdgpu_waves_per_eu(2, 2)))
void rnn_scan(const float* __restrict__ W_hh,   // [U_, U_]
              float* __restrict__ out) {        // [B_, T_, U_]: xW in, h out
    const int b    = (int)blockIdx.x;           // batch
    const int tid  = (int)threadIdx.x;
    const int w    = tid >> 6;                  // wave 0..7: cols [32w, 32w+32)
    const int lane = tid & 63;
    const int g    = lane >> 4;                 // k-group 0..3
    const int c    = lane & 15;                 // col within n-tile / D col
    const int n0   = w * 32;

    __shared__ float buf[2][CH_][U_];               // 32 KB xw in / h out
    __shared__ __align__(16) _Float16 hl[2][U_];    // 2 x 512 B h state

    // B fragments: bf[kt][nt] elem j = W_hh[kt*32 + g*8 + j][n0 + nt*16 + c]
    // (same k-slot<->lane mapping as validated R2 kernel)
    f16x8 bf[8][2];
    #pragma unroll
    for (int kt = 0; kt < 8; ++kt) {
        #pragma unroll
        for (int nt = 0; nt < 2; ++nt) {
            f16x8 v;
            #pragma unroll
            for (int j = 0; j < 8; ++j)
                v[j] = (_Float16)W_hh[(size_t)(kt * 32 + g * 8 + j) * U_
                                      + (n0 + nt * 16 + c)];
            bf[kt][nt] = v;
        }
    }

    if (tid < 128) ((float*)&hl[0][0])[tid] = 0.f;   // zero h (512 B)

    float* gbase = out + (size_t)b * T_ * U_;
    float* bufflat = &buf[0][0][0];

    // chunk 0 -> buf[0] (flat 4096 floats, 8/thread, coalesced)
    {
        float4 v0 = *(const float4*)&gbase[8 * tid];
        float4 v1 = *(const float4*)&gbase[8 * tid + 4];
        *(float4*)&bufflat[8 * tid]     = v0;
        *(float4*)&bufflat[8 * tid + 4] = v1;
    }
    __syncthreads();

    // prefetch chunk 1 into registers (lands during chunk 0's 16 steps)
    float4 p0, p1;
    {
        const float* gsrc = gbase + (size_t)CH_ * U_;
        p0 = *(const float4*)&gsrc[8 * tid];
        p1 = *(const float4*)&gsrc[8 * tid + 4];
    }

    // loop-invariant lane addresses
    const char* hrd = (const char*)&hl[0][0] + g * 16;   // A-read base (+64*kt)
    char*       hwr = (char*)&hl[0][0] + (n0 + c) * 2;   // h-write base (+nt*32)

    // step J (within chunk): reads hl[J&1], writes hl[(J&1)^1]
#define STEP(J)                                                               \
    {                                                                         \
        const int RD = ((J) & 1) * 512;                                       \
        const int WR = 512 - RD;                                              \
        const float xw0 = *(const float*)(bufc + (J) * 1024);                 \
        const float xw1 = *(const float*)(bufc + (J) * 1024 + 64);            \
        f32x4 a0 = {0.f, 0.f, 0.f, 0.f};                                      \
        f32x4 a1 = {0.f, 0.f, 0.f, 0.f};                                      \
        _Pragma("unroll") for (int kt = 0; kt < 8; ++kt) {                    \
            f16x8 a = *(const f16x8*)(hrd + RD + 64 * kt);                    \
            a0 = __builtin_amdgcn_mfma_f32_16x16x32_f16(a, bf[kt][0], a0,     \
                                                        0, 0, 0);             \
            a1 = __builtin_amdgcn_mfma_f32_16x16x32_f16(a, bf[kt][1], a1,     \
                                                        0, 0, 0);             \
        }                                                                     \
        const float h0 = fast_tanh2(a0[0] + xw0);                             \
        const float h1 = fast_tanh2(a1[0] + xw1);                             \
        if (g == 0) {                                                         \
            *(float*)(bufc + (J) * 1024)      = h0;                           \
            *(float*)(bufc + (J) * 1024 + 64) = h1;                           \
            *(_Float16*)(hwr + WR)      = (_Float16)h0;                       \
            *(_Float16*)(hwr + WR + 32) = (_Float16)h1;                       \
        }                                                                     \
        asm volatile("s_waitcnt lgkmcnt(0)" ::: "memory");                    \
        __builtin_amdgcn_s_barrier();                                         \
        asm volatile("" ::: "memory");                                        \
    }

    int cur = 0;
    for (int ch = 0; ch < NCH_; ++ch) {
        char* bufc = (char*)bufflat + cur * 16384 + (n0 + c) * 4;

        STEP(0)  STEP(1)  STEP(2)  STEP(3)
        STEP(4)  STEP(5)  STEP(6)  STEP(7)
        STEP(8)  STEP(9)  STEP(10) STEP(11)
        STEP(12) STEP(13) STEP(14) STEP(15)

        // read own dump region (h of chunk ch) into regs — ordered after the
        // last step's barrier, so all waves' h writes are visible.
        float4 d0 = *(const float4*)&bufflat[cur * 4096 + 8 * tid];
        float4 d1 = *(const float4*)&bufflat[cur * 4096 + 8 * tid + 4];

        // stage prefetched chunk ch+1 into the other buffer (vmcnt waited
        // by the compiler here; loads had a whole chunk to land).
        if (ch + 1 < NCH_) {
            *(float4*)&bufflat[(1 - cur) * 4096 + 8 * tid]     = p0;
            *(float4*)&bufflat[(1 - cur) * 4096 + 8 * tid + 4] = p1;
        }

        // boundary barrier: staged xw (and d0/d1 reads) complete; raw
        // s_barrier does NOT drain vmcnt, so the dump stores below and the
        // next prefetch stay in flight across the next chunk's steps.
        asm volatile("s_waitcnt lgkmcnt(0)" ::: "memory");
        __builtin_amdgcn_s_barrier();
        asm volatile("" ::: "memory");

        // dump chunk ch (h) -> global, coalesced
        {
            float* gdst = gbase + (size_t)ch * CH_ * U_;
            *(float4*)&gdst[8 * tid]     = d0;
            *(float4*)&gdst[8 * tid + 4] = d1;
        }
        // issue prefetch for chunk ch+2
        if (ch + 2 < NCH_) {
            const float* gsrc = gbase + (size_t)(ch + 2) * CH_ * U_;
            p0 = *(const float4*)&gsrc[8 * tid];
            p1 = *(const float4*)&gsrc[8 * tid + 4];
        }
        cur ^= 1;
    }
#undef STEP
}

// ---------------------------------------------------------------------------
extern "C" void kernel_launch(void* const* d_in, const int* in_sizes, int n_in,
                              void* d_out, int out_size, void* d_ws, size_t ws_size,
                              hipStream_t stream) {
    const float* inputs = (const float*)d_in[0];   // [B, T, D]
    const float* W_xh   = (const float*)d_in[1];   // [D, U]
    const float* W_hh   = (const float*)d_in[2];   // [U, U]
    const float* b_h    = (const float*)d_in[3];   // [U]
    float* out = (float*)d_out;                    // [B, T, U]

    const int M = B_ * T_;                         // 65536
    dim3 g1(M / BM, U_ / BN);                      // (1024, 4)
    proj_gemm<<<g1, 256, 0, stream>>>(inputs, W_xh, b_h, out);
    rnn_scan<<<B_, NT2_, 0, stream>>>(W_hh, out);
}

// Round 7
// 622.021 us; speedup vs baseline: 1.6974x; 1.0948x over previous
//
#include <hip/hip_runtime.h>
#include <math.h>

#define B_ 64
#define T_ 1024
#define D_ 256
#define U_ 256

typedef __fp16   hf2_t __attribute__((ext_vector_type(2)));  // cvt_pkrtz ret type
typedef _Float16 f16x8 __attribute__((ext_vector_type(8)));
typedef float    f32x4 __attribute__((ext_vector_type(4)));

// ---------------------------------------------------------------------------
// Kernel 1 (testing this round — R4/R5 infra timeouts, R6 compile fix):
// proj = inputs @ W_xh + b_h on the MFMA pipe. f16 operands, f32 accumulate
// (error ~1e-3 pre-tanh << 2e-2 thr).
// 64(M)x64(N) tile, 256 thr = 4 waves; wave w owns n-tile [n0+16w, +16),
// M-rep = 4 (four 16-row tiles), K = 256 staged entirely in LDS.
//   * A tile (64x256) f16 in LDS, XOR-swizzled byte ^= (row&7)<<4 so the
//     fragment ds_read_b128 (16 rows x 4 col-groups) hits all 8 bank slots
//     evenly (b128 floor). Read addr = (vbase ^ kt*64) + mt*8192: the XOR
//     legally folds the swizzle's bit-6 overlap with kt (fields verified).
//   * B fragments (W_xh n-slice) resident in 32 VGPRs, same validated
//     k-slot<->lane mapping as rnn_scan (R2/R3 passed).
//   * cvt_pkrtz f32->f16 packing (validated in R2 h-pack) — union member
//     uses the builtin's native __fp16 vector type (bit-identical to
//     _Float16; R6 failed on the implicit conversion).
// Roofline: 64 MB rd + 64 MB wr ~ 25 us; MFMA ~1 us; expect ~35-45 us
// vs 183 us for the fp32 VALU version.
// ---------------------------------------------------------------------------
__global__ __launch_bounds__(256, 2)
void proj_gemm_mfma(const float* __restrict__ A,      // [M, D_] inputs
                    const float* __restrict__ Bm,     // [D_, U_] W_xh
                    const float* __restrict__ bias,   // [U_]
                    float* __restrict__ C) {          // [M, U_] out
    __shared__ __align__(16) _Float16 As[64 * 256];   // 32 KB, swizzled

    const int tid  = (int)threadIdx.x;
    const int lane = tid & 63;
    const int w    = tid >> 6;          // wave 0..3 -> n-subtile
    const int g    = lane >> 4;         // k-group 0..3
    const int c    = lane & 15;         // col within n-tile
    const int m0   = (int)blockIdx.x * 64;
    const int n0   = (int)blockIdx.y * 64 + w * 16;

    // B-fragments: bf[kt] elem j = W_xh[kt*32 + g*8 + j][n0 + c]
    f16x8 bf[8];
    #pragma unroll
    for (int kt = 0; kt < 8; ++kt) {
        f16x8 v;
        #pragma unroll
        for (int j = 0; j < 8; ++j)
            v[j] = (_Float16)Bm[(kt * 32 + g * 8 + j) * U_ + n0 + c];
        bf[kt] = v;
    }

    // stage A tile: 2048 x 16B chunks; thread does 8. Coalesced f32 loads,
    // pkrtz pack, swizzled b128 LDS write.
    #pragma unroll
    for (int i = 0; i < 8; ++i) {
        const int chunk = tid + 256 * i;
        const int row   = chunk >> 5;            // 0..63
        const int k8    = (chunk & 31) * 8;      // first of 8 k's
        const float4 f0 = *(const float4*)&A[(size_t)(m0 + row) * D_ + k8];
        const float4 f1 = *(const float4*)&A[(size_t)(m0 + row) * D_ + k8 + 4];
        union { hf2_t p[4]; f16x8 v; } u;
        u.p[0] = __builtin_amdgcn_cvt_pkrtz(f0.x, f0.y);
        u.p[1] = __builtin_amdgcn_cvt_pkrtz(f0.z, f0.w);
        u.p[2] = __builtin_amdgcn_cvt_pkrtz(f1.x, f1.y);
        u.p[3] = __builtin_amdgcn_cvt_pkrtz(f1.z, f1.w);
        *(f16x8*)((char*)As + row * 512 + ((k8 * 2) ^ ((row & 7) << 4))) = u.v;
    }
    __syncthreads();

    // A-fragment read addresses: want byte (mt*16+c)*512 +
    // ((kt*64 + g*16) ^ ((c&7)<<4)). vbase ^ (kt*64) + mt*8192 realizes it
    // (swizzle bits 4-6; kt*64 bits 6-8; row*512 bits >=9 - disjoint except
    // bit 6, which XOR handles exactly).
    const int swz   = (lane & 7) << 4;
    const int vbase = c * 512 + ((g * 16) ^ swz);

    f32x4 acc[4];
    #pragma unroll
    for (int mt = 0; mt < 4; ++mt) acc[mt] = f32x4{0.f, 0.f, 0.f, 0.f};

    #pragma unroll
    for (int kt = 0; kt < 8; ++kt) {
        const char* ap = (const char*)As + (vbase ^ (kt * 64));
        #pragma unroll
        for (int mt = 0; mt < 4; ++mt) {
            f16x8 a = *(const f16x8*)(ap + mt * 8192);
            acc[mt] = __builtin_amdgcn_mfma_f32_16x16x32_f16(a, bf[kt],
                                                             acc[mt], 0, 0, 0);
        }
    }

    const float bb = bias[n0 + c];
    #pragma unroll
    for (int mt = 0; mt < 4; ++mt) {
        #pragma unroll
        for (int r = 0; r < 4; ++r) {
            const int row = m0 + mt * 16 + g * 4 + r;   // D: row=(lane>>4)*4+r
            C[(size_t)row * U_ + n0 + c] = acc[mt][r] + bb;
        }
    }
}

// ---------------------------------------------------------------------------
// branch-free fast tanh: tanh(x) = 1 - 2/(1 + e^{2x}). (validated R2)
// ---------------------------------------------------------------------------
__device__ __forceinline__ float fast_tanh2(float x) {
    float e = __expf(2.0f * x);
    return 1.0f - 2.0f * __builtin_amdgcn_rcpf(e + 1.0f);
}

// ---------------------------------------------------------------------------
// Kernel 2: recurrence on the MFMA pipe, 64 blocks (1 batch each, 64 CUs).
// (unchanged from R3 — passed at 498 us, ~44% MfmaUtil on active CUs)
// ---------------------------------------------------------------------------
#define CH_  16
#define NCH_ (T_ / CH_)
#define NT2_ 512

__global__ __launch_bounds__(NT2_) __attribute__((amdgpu_waves_per_eu(2, 2)))
void rnn_scan(const float* __restrict__ W_hh,   // [U_, U_]
              float* __restrict__ out) {        // [B_, T_, U_]: xW in, h out
    const int b    = (int)blockIdx.x;           // batch
    const int tid  = (int)threadIdx.x;
    const int w    = tid >> 6;                  // wave 0..7: cols [32w, 32w+32)
    const int lane = tid & 63;
    const int g    = lane >> 4;                 // k-group 0..3
    const int c    = lane & 15;                 // col within n-tile / D col
    const int n0   = w * 32;

    __shared__ float buf[2][CH_][U_];               // 32 KB xw in / h out
    __shared__ __align__(16) _Float16 hl[2][U_];    // 2 x 512 B h state

    // B fragments: bf[kt][nt] elem j = W_hh[kt*32 + g*8 + j][n0 + nt*16 + c]
    f16x8 bf[8][2];
    #pragma unroll
    for (int kt = 0; kt < 8; ++kt) {
        #pragma unroll
        for (int nt = 0; nt < 2; ++nt) {
            f16x8 v;
            #pragma unroll
            for (int j = 0; j < 8; ++j)
                v[j] = (_Float16)W_hh[(size_t)(kt * 32 + g * 8 + j) * U_
                                      + (n0 + nt * 16 + c)];
            bf[kt][nt] = v;
        }
    }

    if (tid < 128) ((float*)&hl[0][0])[tid] = 0.f;   // zero h (512 B)

    float* gbase = out + (size_t)b * T_ * U_;
    float* bufflat = &buf[0][0][0];

    // chunk 0 -> buf[0] (flat 4096 floats, 8/thread, coalesced)
    {
        float4 v0 = *(const float4*)&gbase[8 * tid];
        float4 v1 = *(const float4*)&gbase[8 * tid + 4];
        *(float4*)&bufflat[8 * tid]     = v0;
        *(float4*)&bufflat[8 * tid + 4] = v1;
    }
    __syncthreads();

    // prefetch chunk 1 into registers (lands during chunk 0's 16 steps)
    float4 p0, p1;
    {
        const float* gsrc = gbase + (size_t)CH_ * U_;
        p0 = *(const float4*)&gsrc[8 * tid];
        p1 = *(const float4*)&gsrc[8 * tid + 4];
    }

    // loop-invariant lane addresses
    const char* hrd = (const char*)&hl[0][0] + g * 16;   // A-read base (+64*kt)
    char*       hwr = (char*)&hl[0][0] + (n0 + c) * 2;   // h-write base (+nt*32)

    // step J (within chunk): reads hl[J&1], writes hl[(J&1)^1]
#define STEP(J)                                                               \
    {                                                                         \
        const int RD = ((J) & 1) * 512;                                       \
        const int WR = 512 - RD;                                              \
        const float xw0 = *(const float*)(bufc + (J) * 1024);                 \
        const float xw1 = *(const float*)(bufc + (J) * 1024 + 64);            \
        f32x4 a0 = {0.f, 0.f, 0.f, 0.f};                                      \
        f32x4 a1 = {0.f, 0.f, 0.f, 0.f};                                      \
        _Pragma("unroll") for (int kt = 0; kt < 8; ++kt) {                    \
            f16x8 a = *(const f16x8*)(hrd + RD + 64 * kt);                    \
            a0 = __builtin_amdgcn_mfma_f32_16x16x32_f16(a, bf[kt][0], a0,     \
                                                        0, 0, 0);             \
            a1 = __builtin_amdgcn_mfma_f32_16x16x32_f16(a, bf[kt][1], a1,     \
                                                        0, 0, 0);             \
        }                                                                     \
        const float h0 = fast_tanh2(a0[0] + xw0);                             \
        const float h1 = fast_tanh2(a1[0] + xw1);                             \
        if (g == 0) {                                                         \
            *(float*)(bufc + (J) * 1024)      = h0;                           \
            *(float*)(bufc + (J) * 1024 + 64) = h1;                           \
            *(_Float16*)(hwr + WR)      = (_Float16)h0;                       \
            *(_Float16*)(hwr + WR + 32) = (_Float16)h1;                       \
        }                                                                     \
        asm volatile("s_waitcnt lgkmcnt(0)" ::: "memory");                    \
        __builtin_amdgcn_s_barrier();                                         \
        asm volatile("" ::: "memory");                                        \
    }

    int cur = 0;
    for (int ch = 0; ch < NCH_; ++ch) {
        char* bufc = (char*)bufflat + cur * 16384 + (n0 + c) * 4;

        STEP(0)  STEP(1)  STEP(2)  STEP(3)
        STEP(4)  STEP(5)  STEP(6)  STEP(7)
        STEP(8)  STEP(9)  STEP(10) STEP(11)
        STEP(12) STEP(13) STEP(14) STEP(15)

        // read own dump region (h of chunk ch) into regs — ordered after the
        // last step's barrier, so all waves' h writes are visible.
        float4 d0 = *(const float4*)&bufflat[cur * 4096 + 8 * tid];
        float4 d1 = *(const float4*)&bufflat[cur * 4096 + 8 * tid + 4];

        // stage prefetched chunk ch+1 into the other buffer (vmcnt waited
        // by the compiler here; loads had a whole chunk to land).
        if (ch + 1 < NCH_) {
            *(float4*)&bufflat[(1 - cur) * 4096 + 8 * tid]     = p0;
            *(float4*)&bufflat[(1 - cur) * 4096 + 8 * tid + 4] = p1;
        }

        // boundary barrier: staged xw (and d0/d1 reads) complete; raw
        // s_barrier does NOT drain vmcnt, so the dump stores below and the
        // next prefetch stay in flight across the next chunk's steps.
        asm volatile("s_waitcnt lgkmcnt(0)" ::: "memory");
        __builtin_amdgcn_s_barrier();
        asm volatile("" ::: "memory");

        // dump chunk ch (h) -> global, coalesced
        {
            float* gdst = gbase + (size_t)ch * CH_ * U_;
            *(float4*)&gdst[8 * tid]     = d0;
            *(float4*)&gdst[8 * tid + 4] = d1;
        }
        // issue prefetch for chunk ch+2
        if (ch + 2 < NCH_) {
            const float* gsrc = gbase + (size_t)(ch + 2) * CH_ * U_;
            p0 = *(const float4*)&gsrc[8 * tid];
            p1 = *(const float4*)&gsrc[8 * tid + 4];
        }
        cur ^= 1;
    }
#undef STEP
}

// ---------------------------------------------------------------------------
extern "C" void kernel_launch(void* const* d_in, const int* in_sizes, int n_in,
                              void* d_out, int out_size, void* d_ws, size_t ws_size,
                              hipStream_t stream) {
    const float* inputs = (const float*)d_in[0];   // [B, T, D]
    const float* W_xh   = (const float*)d_in[1];   // [D, U]
    const float* W_hh   = (const float*)d_in[2];   // [U, U]
    const float* b_h    = (const float*)d_in[3];   // [U]
    float* out = (float*)d_out;                    // [B, T, U]

    const int M = B_ * T_;                         // 65536
    dim3 g1(M / 64, U_ / 64);                      // (1024, 4)
    proj_gemm_mfma<<<g1, 256, 0, stream>>>(inputs, W_xh, b_h, out);
    rnn_scan<<<B_, NT2_, 0, stream>>>(W_hh, out);
}

// Round 8
// 580.072 us; speedup vs baseline: 1.8201x; 1.0723x over previous
//
#include <hip/hip_runtime.h>
#include <math.h>

#define B_ 64
#define T_ 1024
#define D_ 256
#define U_ 256

typedef __fp16   hf2_t __attribute__((ext_vector_type(2)));  // cvt_pkrtz ret type
typedef _Float16 f16x8 __attribute__((ext_vector_type(8)));
typedef float    f32x4 __attribute__((ext_vector_type(4)));

// ---------------------------------------------------------------------------
// branch-free fast tanh: tanh(x) = 1 - 2/(1 + e^{2x}). (validated R2/R3/R7)
// ---------------------------------------------------------------------------
__device__ __forceinline__ float fast_tanh2(float x) {
    float e = __expf(2.0f * x);
    return 1.0f - 2.0f * __builtin_amdgcn_rcpf(e + 1.0f);
}

// ---------------------------------------------------------------------------
// SINGLE fused kernel this round. 64 blocks (1 batch each), 512 thr = 8 waves.
// Changes vs R7 (both target measured costs):
//  1. proj_gemm fused away (was 114 us, latency-bound at 4096 tiny blocks):
//     per 16-step chunk, prefetch the INPUTS chunk instead of xW, stage it
//     f16-swizzled into Ax (same layout/swizzle R7's proj validated), and at
//     the chunk boundary each wave computes xw = inputs@W_xh + b via 16 MFMA
//     with resident W_xh fragments, writing D straight into the xw LDS buf.
//     ~400 cyc per boundary (~11 us total) vs a 114 us extra dispatch.
//  2. STEP's 8-deep dependent MFMA chain split into 2x4-deep independent
//     chains per n-tile (same 32 MFMA issued; dep latency ~260 -> ~130 cyc;
//     measured step was 1190 cyc, chain was the longest pole after ds_read).
// Scan structure (R3-validated): replicated-row MFMA, broadcast b128 A-reads
// from 512 B h buffer, double-buffered hl -> ONE raw s_barrier (lgkm-only
// drain) per step, chunked global I/O with register prefetch.
// ---------------------------------------------------------------------------
#define CH_  16
#define NCH_ (T_ / CH_)
#define NT2_ 512

__global__ __launch_bounds__(NT2_) __attribute__((amdgpu_waves_per_eu(2, 2)))
void rnn_fused(const float* __restrict__ inputs,  // [B_, T_, D_]
               const float* __restrict__ W_xh,    // [D_, U_]
               const float* __restrict__ W_hh,    // [U_, U_]
               const float* __restrict__ b_h,     // [U_]
               float* __restrict__ out) {         // [B_, T_, U_] h out
    const int b    = (int)blockIdx.x;           // batch
    const int tid  = (int)threadIdx.x;
    const int w    = tid >> 6;                  // wave 0..7: cols [32w, 32w+32)
    const int lane = tid & 63;
    const int g    = lane >> 4;                 // k-group 0..3
    const int c    = lane & 15;                 // col within n-tile
    const int n0   = w * 32;

    __shared__ float buf[2][CH_][U_];               // 32 KB xw in / h out
    __shared__ __align__(16) _Float16 hl[2][U_];    // 2 x 512 B h state
    __shared__ __align__(16) _Float16 Ax[CH_ * D_]; // 8 KB inputs chunk (f16, swz)

    // resident B-fragments (validated mapping): frag[kt][nt] elem j =
    // W[kt*32 + g*8 + j][n0 + nt*16 + c]
    f16x8 whh[8][2], wxh[8][2];
    #pragma unroll
    for (int kt = 0; kt < 8; ++kt) {
        #pragma unroll
        for (int nt = 0; nt < 2; ++nt) {
            f16x8 vh, vx;
            #pragma unroll
            for (int j = 0; j < 8; ++j) {
                const int row = kt * 32 + g * 8 + j;
                const int col = n0 + nt * 16 + c;
                vh[j] = (_Float16)W_hh[(size_t)row * U_ + col];
                vx[j] = (_Float16)W_xh[(size_t)row * U_ + col];
            }
            whh[kt][nt] = vh;
            wxh[kt][nt] = vx;
        }
    }
    const float bb0 = b_h[n0 + c];
    const float bb1 = b_h[n0 + 16 + c];

    if (tid < 128) ((float*)&hl[0][0])[tid] = 0.f;   // zero h (512 B)

    const float* ibase = inputs + (size_t)b * T_ * D_;
    float* gbase = out + (size_t)b * T_ * U_;
    float* bufflat = &buf[0][0][0];

    // Ax staging address (thread-invariant): flat float idx 8*tid ->
    // row = tid>>5, k8 = (tid&31)*8; byte = row*512 + ((k8*2) ^ ((row&7)<<4))
    const int srow = tid >> 5;
    const int sk8  = (tid & 31) * 8;
    char* const sdst = (char*)Ax + srow * 512 + ((sk8 * 2) ^ ((srow & 7) << 4));

    // A-fragment read base in Ax (R7-validated): addr = vbaseA ^ (kt*64)
    const int vbaseA = c * 512 + ((g * 16) ^ ((c & 7) << 4));

#define PACK8(DST, F0, F1)                                                    \
    {                                                                         \
        union { hf2_t p[4]; f16x8 v; } u;                                     \
        u.p[0] = __builtin_amdgcn_cvt_pkrtz((F0).x, (F0).y);                  \
        u.p[1] = __builtin_amdgcn_cvt_pkrtz((F0).z, (F0).w);                  \
        u.p[2] = __builtin_amdgcn_cvt_pkrtz((F1).x, (F1).y);                  \
        u.p[3] = __builtin_amdgcn_cvt_pkrtz((F1).z, (F1).w);                  \
        *(f16x8*)(DST) = u.v;                                                 \
    }

    // projection: xw chunk = Ax @ W_xh + b -> buf[PB] (split 4-deep chains)
#define PROJECT(PB)                                                           \
    {                                                                         \
        f32x4 q0 = {0.f,0.f,0.f,0.f}, q1 = {0.f,0.f,0.f,0.f};                 \
        f32x4 q2 = {0.f,0.f,0.f,0.f}, q3 = {0.f,0.f,0.f,0.f};                 \
        _Pragma("unroll") for (int kt = 0; kt < 4; ++kt) {                    \
            f16x8 a = *(const f16x8*)((const char*)Ax + (vbaseA ^ (kt * 64)));\
            q0 = __builtin_amdgcn_mfma_f32_16x16x32_f16(a, wxh[kt][0], q0, 0, 0, 0); \
            q1 = __builtin_amdgcn_mfma_f32_16x16x32_f16(a, wxh[kt][1], q1, 0, 0, 0); \
        }                                                                     \
        _Pragma("unroll") for (int kt = 4; kt < 8; ++kt) {                    \
            f16x8 a = *(const f16x8*)((const char*)Ax + (vbaseA ^ (kt * 64)));\
            q2 = __builtin_amdgcn_mfma_f32_16x16x32_f16(a, wxh[kt][0], q2, 0, 0, 0); \
            q3 = __builtin_amdgcn_mfma_f32_16x16x32_f16(a, wxh[kt][1], q3, 0, 0, 0); \
        }                                                                     \
        _Pragma("unroll") for (int r = 0; r < 4; ++r) {                       \
            buf[PB][g * 4 + r][n0 + c]      = q0[r] + q2[r] + bb0;            \
            buf[PB][g * 4 + r][n0 + 16 + c] = q1[r] + q3[r] + bb1;            \
        }                                                                     \
    }

    // ---- prologue: stage inputs chunk 0 -> Ax, project -> buf[0]
    {
        float4 f0 = *(const float4*)&ibase[8 * tid];
        float4 f1 = *(const float4*)&ibase[8 * tid + 4];
        PACK8(sdst, f0, f1)
    }
    __syncthreads();
    PROJECT(0)
    // prefetch inputs chunk 1 into registers
    float4 p0, p1;
    {
        const float* gsrc = ibase + (size_t)CH_ * D_;
        p0 = *(const float4*)&gsrc[8 * tid];
        p1 = *(const float4*)&gsrc[8 * tid + 4];
    }
    asm volatile("s_waitcnt lgkmcnt(0)" ::: "memory");
    __builtin_amdgcn_s_barrier();
    asm volatile("" ::: "memory");

    // loop-invariant lane addresses for the scan
    const char* hrd = (const char*)&hl[0][0] + g * 16;   // A-read base (+64*kt)
    char*       hwr = (char*)&hl[0][0] + (n0 + c) * 2;   // h-write base (+nt*32)

    // step J: reads hl[J&1], writes hl[(J&1)^1]; 2x4-deep chains per n-tile
#define STEP(J)                                                               \
    {                                                                         \
        const int RD = ((J) & 1) * 512;                                       \
        const int WR = 512 - RD;                                              \
        const float xw0 = *(const float*)(bufc + (J) * 1024);                 \
        const float xw1 = *(const float*)(bufc + (J) * 1024 + 64);            \
        f32x4 a0 = {0.f,0.f,0.f,0.f}, a1 = {0.f,0.f,0.f,0.f};                 \
        f32x4 c0 = {0.f,0.f,0.f,0.f}, c1 = {0.f,0.f,0.f,0.f};                 \
        _Pragma("unroll") for (int kt = 0; kt < 4; ++kt) {                    \
            f16x8 a = *(const f16x8*)(hrd + RD + 64 * kt);                    \
            a0 = __builtin_amdgcn_mfma_f32_16x16x32_f16(a, whh[kt][0], a0, 0, 0, 0); \
            a1 = __builtin_amdgcn_mfma_f32_16x16x32_f16(a, whh[kt][1], a1, 0, 0, 0); \
        }                                                                     \
        _Pragma("unroll") for (int kt = 4; kt < 8; ++kt) {                    \
            f16x8 a = *(const f16x8*)(hrd + RD + 64 * kt);                    \
            c0 = __builtin_amdgcn_mfma_f32_16x16x32_f16(a, whh[kt][0], c0, 0, 0, 0); \
            c1 = __builtin_amdgcn_mfma_f32_16x16x32_f16(a, whh[kt][1], c1, 0, 0, 0); \
        }                                                                     \
        const float h0 = fast_tanh2(a0[0] + c0[0] + xw0);                     \
        const float h1 = fast_tanh2(a1[0] + c1[0] + xw1);                     \
        if (g == 0) {                                                         \
            *(float*)(bufc + (J) * 1024)      = h0;                           \
            *(float*)(bufc + (J) * 1024 + 64) = h1;                           \
            *(_Float16*)(hwr + WR)      = (_Float16)h0;                       \
            *(_Float16*)(hwr + WR + 32) = (_Float16)h1;                       \
        }                                                                     \
        asm volatile("s_waitcnt lgkmcnt(0)" ::: "memory");                    \
        __builtin_amdgcn_s_barrier();                                         \
        asm volatile("" ::: "memory");                                        \
    }

    int cur = 0;
    for (int ch = 0; ch < NCH_; ++ch) {
        char* bufc = (char*)bufflat + cur * 16384 + (n0 + c) * 4;

        STEP(0)  STEP(1)  STEP(2)  STEP(3)
        STEP(4)  STEP(5)  STEP(6)  STEP(7)
        STEP(8)  STEP(9)  STEP(10) STEP(11)
        STEP(12) STEP(13) STEP(14) STEP(15)

        // ---- chunk boundary ----
        // h of chunk ch -> regs (all waves' h writes visible after STEP(15))
        float4 d0 = *(const float4*)&bufflat[cur * 4096 + 8 * tid];
        float4 d1 = *(const float4*)&bufflat[cur * 4096 + 8 * tid + 4];

        // stage prefetched inputs chunk ch+1 -> Ax (f16, swizzled)
        if (ch + 1 < NCH_) PACK8(sdst, p0, p1)

        asm volatile("s_waitcnt lgkmcnt(0)" ::: "memory");
        __builtin_amdgcn_s_barrier();          // Ax visible; d reads settled
        asm volatile("" ::: "memory");

        // project xw chunk ch+1 into the other buffer
        if (ch + 1 < NCH_) PROJECT(1 - cur)

        // dump h chunk ch -> global, coalesced (vmcnt never drained here)
        {
            float* gdst = gbase + (size_t)ch * CH_ * U_;
            *(float4*)&gdst[8 * tid]     = d0;
            *(float4*)&gdst[8 * tid + 4] = d1;
        }
        // prefetch inputs chunk ch+2
        if (ch + 2 < NCH_) {
            const float* gsrc = ibase + (size_t)(ch + 2) * CH_ * D_;
            p0 = *(const float4*)&gsrc[8 * tid];
            p1 = *(const float4*)&gsrc[8 * tid + 4];
        }

        asm volatile("s_waitcnt lgkmcnt(0)" ::: "memory");
        __builtin_amdgcn_s_barrier();          // projected xw visible
        asm volatile("" ::: "memory");

        cur ^= 1;
    }
#undef STEP
#undef PROJECT
#undef PACK8
}

// ---------------------------------------------------------------------------
extern "C" void kernel_launch(void* const* d_in, const int* in_sizes, int n_in,
                              void* d_out, int out_size, void* d_ws, size_t ws_size,
                              hipStream_t stream) {
    const float* inputs = (const float*)d_in[0];   // [B, T, D]
    const float* W_xh   = (const float*)d_in[1];   // [D, U]
    const float* W_hh   = (const float*)d_in[2];   // [U, U]
    const float* b_h    = (const float*)d_in[3];   // [U]
    float* out = (float*)d_out;                    // [B, T, U]

    rnn_fused<<<B_, NT2_, 0, stream>>>(inputs, W_xh, W_hh, b_h, out);
}